// Round 3
// baseline (301.804 us; speedup 1.0000x reference)
//
#include <hip/hip_runtime.h>
#include <math.h>

#define K_CODES 512
#define D_DIM   64

// numpy pairwise-sum emulation for n=64 contiguous fp32, AVX512 build
// (EPYC Zen4/5 host): r0..r3 = x[0:16],x[16:32],x[32:48],x[48:64];
// sum = (r0+r1)+(r2+r3) lanewise; then _mm512_reduce_add_ps halving tree.
// All adds guarded with __fadd_rn so fp-contract can't alter rounding.
__device__ __forceinline__ float np_sum64_avx512(const float* sq) {
    float L[16];
#pragma unroll
    for (int j = 0; j < 16; ++j)
        L[j] = __fadd_rn(__fadd_rn(sq[j], sq[j + 16]),
                         __fadd_rn(sq[j + 32], sq[j + 48]));
    float m[8];
#pragma unroll
    for (int j = 0; j < 8; ++j) m[j] = __fadd_rn(L[j], L[j + 8]);
    float n4[4];
#pragma unroll
    for (int j = 0; j < 4; ++j) n4[j] = __fadd_rn(m[j], m[j + 4]);
    float o0 = __fadd_rn(n4[0], n4[2]);
    float o1 = __fadd_rn(n4[1], n4[3]);
    return __fadd_rn(o0, o1);
}

// ||e_k||^2 with the same numpy tree (squares rounded first, like cb*cb temp).
__global__ __launch_bounds__(256) void vq_norms_kernel(const float* __restrict__ cb,
                                                       float* __restrict__ norms) {
    int k = blockIdx.x * blockDim.x + threadIdx.x;
    if (k >= K_CODES) return;
    const float* row = cb + (size_t)k * D_DIM;
    float sq[D_DIM];
#pragma unroll
    for (int i = 0; i < D_DIM; ++i) sq[i] = __fmul_rn(row[i], row[i]);
    norms[k] = np_sum64_avx512(sq);
}

// One thread per point. Emulates the numpy fp32 reference bit-for-bit:
//   dists_k = fl( fl( sz - fl(2*dot_k) ) + se_k ),  argmin = first min.
// dot_k: sequential ascending-k FMA chain (BLAS microkernel accumulation).
// sz:    numpy AVX512 pairwise tree of fl(z_i^2).
// NOTE: deliberately NOT more accurate than the reference — the reference's
// own ULP(64) rounding grid decides ~200 near-tie points; we must round the
// same way (R1/R2 post-mortem: identical mismatch sets = reference noise).
__global__ __launch_bounds__(256) void vq_argmin_kernel(
        const float* __restrict__ z, const float* __restrict__ cb,
        const float* __restrict__ norms, int* __restrict__ out, int n) {
    int t = blockIdx.x * 256 + threadIdx.x;
    if (t >= n) return;

    // Load z row (coalesced float4), keep as scalar regs.
    float zr[D_DIM];
    {
        const float4* zp = reinterpret_cast<const float4*>(z + (size_t)t * D_DIM);
#pragma unroll
        for (int i = 0; i < 16; ++i) {
            float4 v = zp[i];
            zr[4 * i + 0] = v.x; zr[4 * i + 1] = v.y;
            zr[4 * i + 2] = v.z; zr[4 * i + 3] = v.w;
        }
    }

    // sz = np.sum(flat*flat, axis=1): squares rounded individually, then tree.
    float sq[D_DIM];
#pragma unroll
    for (int i = 0; i < D_DIM; ++i) sq[i] = __fmul_rn(zr[i], zr[i]);
    const float sz = np_sum64_avx512(sq);

    float best = INFINITY;
    int   bi   = 0;

    // k-block of 4: four independent sequential fma chains (ILP to hide
    // 4-cyc VALU latency) while keeping each chain's k-order exact.
    for (int k0 = 0; k0 < K_CODES; k0 += 4) {
        const float* e0 = cb + ((size_t)(k0 + 0) << 6);
        const float* e1 = cb + ((size_t)(k0 + 1) << 6);
        const float* e2 = cb + ((size_t)(k0 + 2) << 6);
        const float* e3 = cb + ((size_t)(k0 + 3) << 6);
        float a0 = 0.f, a1 = 0.f, a2 = 0.f, a3 = 0.f;
#pragma unroll
        for (int i = 0; i < D_DIM; ++i) {
            float zi = zr[i];
            a0 = fmaf(zi, e0[i], a0);
            a1 = fmaf(zi, e1[i], a1);
            a2 = fmaf(zi, e2[i], a2);
            a3 = fmaf(zi, e3[i], a3);
        }
        // dists = fl(fl(sz - fl(2*dot)) + se), evaluated in ascending k order.
        float s0 = __fadd_rn(__fsub_rn(sz, __fmul_rn(2.0f, a0)), norms[k0 + 0]);
        float s1 = __fadd_rn(__fsub_rn(sz, __fmul_rn(2.0f, a1)), norms[k0 + 1]);
        float s2 = __fadd_rn(__fsub_rn(sz, __fmul_rn(2.0f, a2)), norms[k0 + 2]);
        float s3 = __fadd_rn(__fsub_rn(sz, __fmul_rn(2.0f, a3)), norms[k0 + 3]);
        if (s0 < best) { best = s0; bi = k0 + 0; }
        if (s1 < best) { best = s1; bi = k0 + 1; }
        if (s2 < best) { best = s2; bi = k0 + 2; }
        if (s3 < best) { best = s3; bi = k0 + 3; }
    }
    out[t] = bi;
}

extern "C" void kernel_launch(void* const* d_in, const int* in_sizes, int n_in,
                              void* d_out, int out_size, void* d_ws, size_t ws_size,
                              hipStream_t stream) {
    const float* z  = (const float*)d_in[0];
    const float* cb = (const float*)d_in[1];
    int n = in_sizes[0] / D_DIM;           // 131072 points
    float* norms = (float*)d_ws;           // 512 floats of scratch
    int* out = (int*)d_out;

    vq_norms_kernel<<<(K_CODES + 255) / 256, 256, 0, stream>>>(cb, norms);
    vq_argmin_kernel<<<(n + 255) / 256, 256, 0, stream>>>(z, cb, norms, out, n);
}

// Round 4
// 170.866 us; speedup vs baseline: 1.7663x; 1.7663x over previous
//
#include <hip/hip_runtime.h>
#include <math.h>

#define K_CODES 512
#define D_DIM   64
#define CHUNK   128   // codes per LDS chunk (32 KB)

// numpy pairwise-sum emulation for n=64 contiguous fp32 (AVX512 host build):
// lanes L[j] = (x[j]+x[j+16]) + (x[j+32]+x[j+48]); then halving reduce tree.
// FROZEN — this exact tree passed bit-exact in R3. All adds __fadd_rn-guarded.
__device__ __forceinline__ float np_sum64_avx512(const float* sq) {
    float L[16];
#pragma unroll
    for (int j = 0; j < 16; ++j)
        L[j] = __fadd_rn(__fadd_rn(sq[j], sq[j + 16]),
                         __fadd_rn(sq[j + 32], sq[j + 48]));
    float m[8];
#pragma unroll
    for (int j = 0; j < 8; ++j) m[j] = __fadd_rn(L[j], L[j + 8]);
    float n4[4];
#pragma unroll
    for (int j = 0; j < 4; ++j) n4[j] = __fadd_rn(m[j], m[j + 4]);
    float o0 = __fadd_rn(n4[0], n4[2]);
    float o1 = __fadd_rn(n4[1], n4[3]);
    return __fadd_rn(o0, o1);
}

// ||e_k||^2 with the same numpy tree (squares rounded first). FROZEN (R3).
__global__ __launch_bounds__(256) void vq_norms_kernel(const float* __restrict__ cb,
                                                       float* __restrict__ norms) {
    int k = blockIdx.x * blockDim.x + threadIdx.x;
    if (k >= K_CODES) return;
    const float* row = cb + (size_t)k * D_DIM;
    float sq[D_DIM];
#pragma unroll
    for (int i = 0; i < D_DIM; ++i) sq[i] = __fmul_rn(row[i], row[i]);
    norms[k] = np_sum64_avx512(sq);
}

// One thread per point, z row pinned in VGPRs (launch_bounds(256,2) -> VGPR
// cap 256; R3's heuristic 48-VGPR choice forced z out of registers and made
// the loop vmem-latency-bound at 44% VALUBusy). Codebook staged through LDS
// in 32KB chunks; compute reads are wave-uniform -> broadcast, conflict-free.
// Arithmetic order FROZEN from R3 (bit-exact vs numpy fp32 reference):
//   dot_k = sequential ascending-i fmaf chain; dists = fl(fl(sz-fl(2dot))+se).
__global__ __launch_bounds__(256, 2) void vq_argmin_kernel(
        const float* __restrict__ z, const float* __restrict__ cb,
        const float* __restrict__ norms, int* __restrict__ out, int n) {
    __shared__ float4 cb4[CHUNK * 16];    // 32 KB: [row][16 float4]
    __shared__ float4 nrm4[CHUNK / 4];    // 512 B
    const float* nrm = (const float*)nrm4;

    const int tid = threadIdx.x;
    const int t   = blockIdx.x * 256 + tid;
    const bool active = (t < n);

    float zr[D_DIM];
    if (active) {
        const float4* zp = reinterpret_cast<const float4*>(z + (size_t)t * D_DIM);
#pragma unroll
        for (int i = 0; i < 16; ++i) {
            float4 v = zp[i];
            zr[4 * i + 0] = v.x; zr[4 * i + 1] = v.y;
            zr[4 * i + 2] = v.z; zr[4 * i + 3] = v.w;
        }
    } else {
#pragma unroll
        for (int i = 0; i < D_DIM; ++i) zr[i] = 0.f;
    }

    // sz = np.sum(flat*flat, axis=1): squares rounded individually, then tree.
    float sq[D_DIM];
#pragma unroll
    for (int i = 0; i < D_DIM; ++i) sq[i] = __fmul_rn(zr[i], zr[i]);
    const float sz = np_sum64_avx512(sq);

    float best = INFINITY;
    int   bi   = 0;

    for (int c0 = 0; c0 < K_CODES; c0 += CHUNK) {
        __syncthreads();   // previous chunk fully consumed
        {
            // Stage 128 codes (2048 float4) + their norms, coalesced.
            const float4* src = reinterpret_cast<const float4*>(cb + (size_t)c0 * D_DIM);
#pragma unroll
            for (int j = 0; j < (CHUNK * 16) / 256; ++j)   // 8 float4 per thread
                cb4[tid + j * 256] = src[tid + j * 256];
            if (tid < CHUNK / 4)
                nrm4[tid] = reinterpret_cast<const float4*>(norms + c0)[tid];
        }
        __syncthreads();

        for (int kk = 0; kk < CHUNK; kk += 4) {
            const float4* e0 = cb4 + (kk + 0) * 16;
            const float4* e1 = cb4 + (kk + 1) * 16;
            const float4* e2 = cb4 + (kk + 2) * 16;
            const float4* e3 = cb4 + (kk + 3) * 16;
            float a0 = 0.f, a1 = 0.f, a2 = 0.f, a3 = 0.f;
#pragma unroll
            for (int g = 0; g < 16; ++g) {
                float4 v0 = e0[g], v1 = e1[g], v2 = e2[g], v3 = e3[g];
                float z0 = zr[4 * g + 0], z1 = zr[4 * g + 1];
                float z2 = zr[4 * g + 2], z3 = zr[4 * g + 3];
                a0 = fmaf(z0, v0.x, a0); a0 = fmaf(z1, v0.y, a0);
                a0 = fmaf(z2, v0.z, a0); a0 = fmaf(z3, v0.w, a0);
                a1 = fmaf(z0, v1.x, a1); a1 = fmaf(z1, v1.y, a1);
                a1 = fmaf(z2, v1.z, a1); a1 = fmaf(z3, v1.w, a1);
                a2 = fmaf(z0, v2.x, a2); a2 = fmaf(z1, v2.y, a2);
                a2 = fmaf(z2, v2.z, a2); a2 = fmaf(z3, v2.w, a2);
                a3 = fmaf(z0, v3.x, a3); a3 = fmaf(z1, v3.y, a3);
                a3 = fmaf(z2, v3.z, a3); a3 = fmaf(z3, v3.w, a3);
            }
            float s0 = __fadd_rn(__fsub_rn(sz, __fmul_rn(2.0f, a0)), nrm[kk + 0]);
            float s1 = __fadd_rn(__fsub_rn(sz, __fmul_rn(2.0f, a1)), nrm[kk + 1]);
            float s2 = __fadd_rn(__fsub_rn(sz, __fmul_rn(2.0f, a2)), nrm[kk + 2]);
            float s3 = __fadd_rn(__fsub_rn(sz, __fmul_rn(2.0f, a3)), nrm[kk + 3]);
            if (s0 < best) { best = s0; bi = c0 + kk + 0; }
            if (s1 < best) { best = s1; bi = c0 + kk + 1; }
            if (s2 < best) { best = s2; bi = c0 + kk + 2; }
            if (s3 < best) { best = s3; bi = c0 + kk + 3; }
        }
    }
    if (active) out[t] = bi;
}

extern "C" void kernel_launch(void* const* d_in, const int* in_sizes, int n_in,
                              void* d_out, int out_size, void* d_ws, size_t ws_size,
                              hipStream_t stream) {
    const float* z  = (const float*)d_in[0];
    const float* cb = (const float*)d_in[1];
    int n = in_sizes[0] / D_DIM;           // 131072 points
    float* norms = (float*)d_ws;           // 512 floats of scratch
    int* out = (int*)d_out;

    vq_norms_kernel<<<(K_CODES + 255) / 256, 256, 0, stream>>>(cb, norms);
    vq_argmin_kernel<<<(n + 255) / 256, 256, 0, stream>>>(z, cb, norms, out, n);
}

// Round 5
// 149.839 us; speedup vs baseline: 2.0142x; 1.1403x over previous
//
#include <hip/hip_runtime.h>
#include <math.h>

#define K_CODES 512
#define D_DIM   64
#define CHUNK   128   // codes staged per LDS chunk (32 KB)
#define TPP     4     // threads (one per wave) cooperating per point
#define PPB     64    // points per block = 256/TPP

// numpy pairwise-sum emulation for n=64 contiguous fp32 (AVX512 host build).
// FROZEN — bit-exact vs the np reference since R3. All adds __fadd_rn-guarded.
__device__ __forceinline__ float np_sum64_avx512(const float* sq) {
    float L[16];
#pragma unroll
    for (int j = 0; j < 16; ++j)
        L[j] = __fadd_rn(__fadd_rn(sq[j], sq[j + 16]),
                         __fadd_rn(sq[j + 32], sq[j + 48]));
    float m[8];
#pragma unroll
    for (int j = 0; j < 8; ++j) m[j] = __fadd_rn(L[j], L[j + 8]);
    float n4[4];
#pragma unroll
    for (int j = 0; j < 4; ++j) n4[j] = __fadd_rn(m[j], m[j + 4]);
    float o0 = __fadd_rn(n4[0], n4[2]);
    float o1 = __fadd_rn(n4[1], n4[3]);
    return __fadd_rn(o0, o1);
}

// ||e_k||^2 with the same numpy tree (squares rounded first). FROZEN (R3).
__global__ __launch_bounds__(256) void vq_norms_kernel(const float* __restrict__ cb,
                                                       float* __restrict__ norms) {
    int k = blockIdx.x * blockDim.x + threadIdx.x;
    if (k >= K_CODES) return;
    const float* row = cb + (size_t)k * D_DIM;
    float sq[D_DIM];
#pragma unroll
    for (int i = 0; i < D_DIM; ++i) sq[i] = __fmul_rn(row[i], row[i]);
    norms[k] = np_sum64_avx512(sq);
}

// K-split x4: block = 64 points x 4 wave-quarters. Wave q scans codes
// [c0+32q, c0+32q+32) of each staged chunk -> 8192 waves total (4/SIMD
// resident at 4 blocks/CU) instead of R4's grid-structural 2 waves/SIMD.
// Per-k arithmetic chains FROZEN (R3 bit-exact); cross-thread merge is
// (value, min-index) -> identical to global ascending-k first-min.
__global__ __launch_bounds__(256, 4) void vq_argmin_kernel(
        const float* __restrict__ z, const float* __restrict__ cb,
        const float* __restrict__ norms, int* __restrict__ out, int n) {
    __shared__ float4 cb4[CHUNK * 16];    // 32 KB: [row][16 float4]
    __shared__ float4 nrm4[CHUNK / 4];    // 512 B
    __shared__ float  rv[256];            // 1 KB  (val reduce)
    __shared__ int    ri[256];            // 1 KB  (idx reduce)
    const float* nrm = (const float*)nrm4;

    const int tid = threadIdx.x;
    const int pl  = tid & (PPB - 1);      // point-local 0..63
    const int q   = tid >> 6;             // wave quarter 0..3 (wave-uniform)
    const int t   = blockIdx.x * PPB + pl;
    const bool active = (t < n);

    float zr[D_DIM];
    if (active) {
        const float4* zp = reinterpret_cast<const float4*>(z + (size_t)t * D_DIM);
#pragma unroll
        for (int i = 0; i < 16; ++i) {
            float4 v = zp[i];
            zr[4 * i + 0] = v.x; zr[4 * i + 1] = v.y;
            zr[4 * i + 2] = v.z; zr[4 * i + 3] = v.w;
        }
    } else {
#pragma unroll
        for (int i = 0; i < D_DIM; ++i) zr[i] = 0.f;
    }

    // sz = np.sum(flat*flat): squares rounded individually, then FROZEN tree.
    float sq[D_DIM];
#pragma unroll
    for (int i = 0; i < D_DIM; ++i) sq[i] = __fmul_rn(zr[i], zr[i]);
    const float sz = np_sum64_avx512(sq);

    float best = INFINITY;
    int   bi   = 0;

    for (int c0 = 0; c0 < K_CODES; c0 += CHUNK) {
        __syncthreads();   // previous chunk fully consumed
        {
            const float4* src = reinterpret_cast<const float4*>(cb + (size_t)c0 * D_DIM);
#pragma unroll
            for (int j = 0; j < (CHUNK * 16) / 256; ++j)   // 8 float4 per thread
                cb4[tid + j * 256] = src[tid + j * 256];
            if (tid < CHUNK / 4)
                nrm4[tid] = reinterpret_cast<const float4*>(norms + c0)[tid];
        }
        __syncthreads();

        const int kbase = q * (CHUNK / TPP);               // 32-code slice
        for (int kk = kbase; kk < kbase + CHUNK / TPP; kk += 4) {
            const float4* e0 = cb4 + (kk + 0) * 16;
            const float4* e1 = cb4 + (kk + 1) * 16;
            const float4* e2 = cb4 + (kk + 2) * 16;
            const float4* e3 = cb4 + (kk + 3) * 16;
            float a0 = 0.f, a1 = 0.f, a2 = 0.f, a3 = 0.f;
#pragma unroll
            for (int g = 0; g < 16; ++g) {
                float4 v0 = e0[g], v1 = e1[g], v2 = e2[g], v3 = e3[g];
                float z0 = zr[4 * g + 0], z1 = zr[4 * g + 1];
                float z2 = zr[4 * g + 2], z3 = zr[4 * g + 3];
                a0 = fmaf(z0, v0.x, a0); a0 = fmaf(z1, v0.y, a0);
                a0 = fmaf(z2, v0.z, a0); a0 = fmaf(z3, v0.w, a0);
                a1 = fmaf(z0, v1.x, a1); a1 = fmaf(z1, v1.y, a1);
                a1 = fmaf(z2, v1.z, a1); a1 = fmaf(z3, v1.w, a1);
                a2 = fmaf(z0, v2.x, a2); a2 = fmaf(z1, v2.y, a2);
                a2 = fmaf(z2, v2.z, a2); a2 = fmaf(z3, v2.w, a2);
                a3 = fmaf(z0, v3.x, a3); a3 = fmaf(z1, v3.y, a3);
                a3 = fmaf(z2, v3.z, a3); a3 = fmaf(z3, v3.w, a3);
            }
            float s0 = __fadd_rn(__fsub_rn(sz, __fmul_rn(2.0f, a0)), nrm[kk + 0]);
            float s1 = __fadd_rn(__fsub_rn(sz, __fmul_rn(2.0f, a1)), nrm[kk + 1]);
            float s2 = __fadd_rn(__fsub_rn(sz, __fmul_rn(2.0f, a2)), nrm[kk + 2]);
            float s3 = __fadd_rn(__fsub_rn(sz, __fmul_rn(2.0f, a3)), nrm[kk + 3]);
            if (s0 < best) { best = s0; bi = c0 + kk + 0; }
            if (s1 < best) { best = s1; bi = c0 + kk + 1; }
            if (s2 < best) { best = s2; bi = c0 + kk + 2; }
            if (s3 < best) { best = s3; bi = c0 + kk + 3; }
        }
    }

    // Exact cross-quarter merge: min value, ties -> lowest index (= first-min).
    rv[tid] = best; ri[tid] = bi;
    __syncthreads();
    if (tid < PPB) {
#pragma unroll
        for (int j = 1; j < TPP; ++j) {
            float v = rv[tid + j * PPB];
            int   id = ri[tid + j * PPB];
            if (v < best || (v == best && id < bi)) { best = v; bi = id; }
        }
        if (active) out[t] = bi;
    }
}

extern "C" void kernel_launch(void* const* d_in, const int* in_sizes, int n_in,
                              void* d_out, int out_size, void* d_ws, size_t ws_size,
                              hipStream_t stream) {
    const float* z  = (const float*)d_in[0];
    const float* cb = (const float*)d_in[1];
    int n = in_sizes[0] / D_DIM;           // 131072 points
    float* norms = (float*)d_ws;           // 512 floats of scratch
    int* out = (int*)d_out;

    vq_norms_kernel<<<(K_CODES + 255) / 256, 256, 0, stream>>>(cb, norms);
    vq_argmin_kernel<<<(n + PPB - 1) / PPB, 256, 0, stream>>>(z, cb, norms, out, n);
}